// Round 5
// baseline (251.868 us; speedup 1.0000x reference)
//
#include <hip/hip_runtime.h>
#include <hip/hip_bf16.h>

typedef __hip_bfloat16 bf16;
typedef __attribute__((ext_vector_type(8))) short bf16x8;
typedef __attribute__((ext_vector_type(4))) float f32x4;

#define NB 8
#define NC 256
#define NQK 32
#define NH 128
#define NW 128
#define NHW 16384
#define QSTR 40    // k_qk Xl stride: 80B = 5*16B aligned

static __device__ __forceinline__ float b2f(bf16 v){ return __bfloat162float(v); }
static __device__ __forceinline__ bf16  f2b(float v){ return __float2bfloat16(v); }
// swizzled element offset in a [128][128] bf16 LDS tile: rows 256B, col XOR'd by (row&7)<<3
// (elem space; preserves 8-elem and 4-elem block alignment). T2 pattern for b128 frag reads.
static __device__ __forceinline__ int swz(int row, int col){ return row*128 + (col ^ ((row&7)<<3)); }

// ---------------- prep: wvb[co][c] bf16, wqkb[o][c] bf16 (o<32: Wq row, o>=32: Wk row) --------
__global__ __launch_bounds__(256) void k_prep(const float* __restrict__ Wq,
                                              const float* __restrict__ Wk,
                                              const float* __restrict__ Wv,
                                              bf16* __restrict__ wvb,
                                              bf16* __restrict__ wqkb){
    int idx = blockIdx.x*256 + threadIdx.x;
    if (idx < 65536){
        wvb[idx] = f2b(Wv[idx]);                  // row-major [co][c]
    } else {
        int i2 = idx - 65536;                     // 0..16383 -> [64][256] flat
        wqkb[i2] = f2b(i2 < 8192 ? Wq[i2] : Wk[i2 - 8192]);
    }
}

// ---------------- qk conv (MFMA): q,k rows [b][p][32] = Wqk * x ----------------
__global__ __launch_bounds__(512) void k_qk(const float* __restrict__ x,
                                            const bf16* __restrict__ wqkb,
                                            const float* __restrict__ bq,
                                            const float* __restrict__ bk,
                                            bf16* __restrict__ qrw,
                                            bf16* __restrict__ krw){
    __shared__ __align__(16) bf16 Xl[256*QSTR];
    int t = threadIdx.x;
    int wv = t >> 6, l = t & 63, lr = l & 15, lg = l >> 4;
    int b = blockIdx.y;
    int p0 = blockIdx.x * 256;
    int q4 = t & 3, pb = ((t >> 2) & 63) * 4, chi = t >> 8;   // chi 0/1
    f32x4 acc[4][2] = {};
    for (int kb = 0; kb < 8; kb++){
        if (kb) __syncthreads();
        #pragma unroll
        for (int it = 0; it < 4; it++){
            int cl = it*8 + chi*4;                // chunk-local c base (lane adds q4)
            const float* xp = x + ((size_t)(b*NC + kb*32 + cl + q4))*NHW + p0 + pb;
            float4 v = *(const float4*)xp;
            float e[4] = {v.x, v.y, v.z, v.w};
            float s1[4], s2[4];
            #pragma unroll
            for (int j=0;j<4;j++){
                float ex = __shfl_xor(e[j^1], 1);
                s1[j] = ((j&1)==(q4&1)) ? e[j] : ex;
            }
            #pragma unroll
            for (int j=0;j<4;j++){
                float ex = __shfl_xor(s1[j^2], 2);
                s2[j] = ((j&2)==(q4&2)) ? s1[j] : ex;
            }
            union { ushort4 u; bf16 h[4]; } pk;
            #pragma unroll
            for (int j=0;j<4;j++) pk.h[j] = f2b(s2[j]);
            *(ushort4*)(Xl + (pb + q4)*QSTR + cl) = pk.u;
        }
        __syncthreads();
        bf16x8 bf_[2];
        #pragma unroll
        for (int nt=0;nt<2;nt++)
            bf_[nt] = *(const bf16x8*)(Xl + (wv*32 + nt*16 + lr)*QSTR + lg*8);
        #pragma unroll
        for (int mt=0;mt<4;mt++){
            bf16x8 af = *(const bf16x8*)(wqkb + (size_t)(mt*16 + lr)*NC + kb*32 + lg*8);
            acc[mt][0] = __builtin_amdgcn_mfma_f32_16x16x32_bf16(af, bf_[0], acc[mt][0], 0,0,0);
            acc[mt][1] = __builtin_amdgcn_mfma_f32_16x16x32_bf16(af, bf_[1], acc[mt][1], 0,0,0);
        }
    }
    #pragma unroll
    for (int mt=0;mt<4;mt++){
        int o0 = mt*16 + lg*4;                        // 0..63
        float4 bb = (mt < 2) ? *(const float4*)(bq + o0)
                             : *(const float4*)(bk + o0 - 32);
        bf16* dst = (mt < 2) ? qrw : krw;
        int oo = (mt < 2) ? o0 : o0 - 32;             // 0..28
        #pragma unroll
        for (int nt=0;nt<2;nt++){
            int p = p0 + wv*32 + nt*16 + lr;
            union { ushort4 u; bf16 h[4]; } pk;
            pk.h[0] = f2b(acc[mt][nt][0] + bb.x);
            pk.h[1] = f2b(acc[mt][nt][1] + bb.y);
            pk.h[2] = f2b(acc[mt][nt][2] + bb.z);
            pk.h[3] = f2b(acc[mt][nt][3] + bb.w);
            *(ushort4*)(dst + ((size_t)b*NHW + p)*NQK + oo) = pk.u;
        }
    }
}

// ---------------- tiled transpose: x fp32 [c][h][w] -> xcm bf16 [c][w][h] ----------------
__global__ __launch_bounds__(256) void k_tr(const float* __restrict__ x,
                                            bf16* __restrict__ xcm){
    __shared__ float tile[32][33];
    int img = blockIdx.y;                 // 0..2047 (b*c)
    int tw = blockIdx.x & 3, th = blockIdx.x >> 2;
    int tx = threadIdx.x, ty = threadIdx.y;   // 32 x 8
    int h0 = th*32, w0 = tw*32;
    const float* src = x + (size_t)img*NHW;
    #pragma unroll
    for (int r=0;r<4;r++)
        tile[ty + r*8][tx] = src[(size_t)(h0+ty+r*8)*NW + w0 + tx];
    __syncthreads();
    bf16* dst = xcm + (size_t)img*NHW;
    #pragma unroll
    for (int r=0;r<4;r++)
        dst[(size_t)(w0+ty+r*8)*NH + h0 + tx] = f2b(tile[tx][ty+r*8]);
}

// ---------------- column attention (MFMA): unnormalized aggH + lH ----------------
// Swizzled [128][128] LDS tiles; xcm staging prefetched one half ahead (reg split);
// agg writes retiled through Xl -> fully coalesced 16B/lane stores.
__global__ __launch_bounds__(512) void k_colagg(const bf16* __restrict__ qrw,
                                                const bf16* __restrict__ krw,
                                                const bf16* __restrict__ xcm,
                                                bf16* __restrict__ agg,
                                                float* __restrict__ lH){
    __shared__ __align__(16) bf16 Pl[16384];
    __shared__ __align__(16) bf16 Xl[16384];
    __shared__ float lsum[128];
    int t = threadIdx.x;
    int wv = t >> 6, l = t & 63, lr = l & 15, lg = l >> 4;
    int w = blockIdx.x, b = blockIdx.y;
    f32x4 zero = {0.f,0.f,0.f,0.f};
    // ---- phase 1: QK^T + exp -> Pl (swizzled), row sums ----
    bf16x8 af = *(const bf16x8*)(qrw + ((size_t)(b*NH + wv*16 + lr)*NW + w)*NQK + lg*8);
    float sreg[4] = {0.f,0.f,0.f,0.f};
    for (int nj=0; nj<8; nj++){
        bf16x8 bfr = *(const bf16x8*)(krw + ((size_t)(b*NH + nj*16 + lr)*NW + w)*NQK + lg*8);
        f32x4 e = __builtin_amdgcn_mfma_f32_16x16x32_bf16(af, bfr, zero, 0,0,0);
        #pragma unroll
        for (int r=0;r<4;r++){
            int i = wv*16 + lg*4 + r;
            int j = nj*16 + lr;
            float pv = (i == j) ? 0.f : __expf(e[r]);
            Pl[swz(i, j)] = f2b(pv);
            sreg[r] += pv;
        }
    }
    // prefetch xcm half0 into regs (coalesced 16B/lane)
    uint4 xg[4];
    #pragma unroll
    for (int it=0;it<4;it++){
        int fl = it*512 + t, c = fl >> 4, seg = fl & 15;
        xg[it] = *(const uint4*)(xcm + ((size_t)(b*NC + c)*NW + w)*NH + seg*8);
    }
    #pragma unroll
    for (int m=1;m<16;m<<=1)
        #pragma unroll
        for (int r=0;r<4;r++) sreg[r] += __shfl_xor(sreg[r], m);
    if (lr == 0){
        #pragma unroll
        for (int r=0;r<4;r++) lsum[wv*16 + lg*4 + r] = sreg[r];
    }
    __syncthreads();
    if (t < 128) lH[((size_t)(b*NH + t))*NW + w] = lsum[t];
    for (int half=0; half<2; half++){
        // write staged half to Xl (swizzled)
        #pragma unroll
        for (int it=0;it<4;it++){
            int fl = it*512 + t, c = fl >> 4, seg = fl & 15;
            *(uint4*)&Xl[c*128 + ((seg*8) ^ ((c&7)<<3))] = xg[it];
        }
        __syncthreads();
        // prefetch next half while computing this one
        if (half == 0){
            #pragma unroll
            for (int it=0;it<4;it++){
                int fl = it*512 + t, c = fl >> 4, seg = fl & 15;
                xg[it] = *(const uint4*)(xcm + ((size_t)(b*NC + 128 + c)*NW + w)*NH + seg*8);
            }
        }
        bf16x8 xa[4];
        #pragma unroll
        for (int kb=0;kb<4;kb++)
            xa[kb] = *(const bf16x8*)&Xl[swz(wv*16 + lr, kb*32 + lg*8)];
        f32x4 acc8[8];
        for (int nj=0;nj<8;nj++){
            acc8[nj] = zero;
            #pragma unroll
            for (int kb=0;kb<4;kb++){
                bf16x8 pb = *(const bf16x8*)&Pl[swz(nj*16 + lr, kb*32 + lg*8)];
                acc8[nj] = __builtin_amdgcn_mfma_f32_16x16x32_bf16(xa[kb], pb, acc8[nj], 0,0,0);
            }
        }
        __syncthreads();   // Xl frag reads done
        // retile accs into Xl (D[c][i] -> [i][c-local])
        #pragma unroll
        for (int nj=0;nj<8;nj++){
            int i = nj*16 + lr, c4 = wv*16 + lg*4;
            union { ushort4 u; bf16 h[4]; } pk;
            #pragma unroll
            for (int r=0;r<4;r++) pk.h[r] = f2b(acc8[nj][r]);
            *(ushort4*)&Xl[i*128 + (c4 ^ ((i&7)<<3))] = pk.u;
        }
        __syncthreads();
        // coalesced agg write (256B/row bursts)
        #pragma unroll
        for (int it=0;it<4;it++){
            int fl = it*512 + t, i = fl >> 4, seg = fl & 15;
            uint4 v = *(const uint4*)&Xl[i*128 + ((seg*8) ^ ((i&7)<<3))];
            *(uint4*)(agg + ((size_t)(b*NHW + i*NW + w))*NC + half*128 + seg*8) = v;
        }
        if (half == 0) __syncthreads();   // retile reads done before restage
    }
}

// ---------------- fused row attention + final conv ----------------
// aggH staged cooperatively into AggL (coalesced, prefetched one half ahead);
// combine is an LDS RMW; swizzled [128][128] tiles throughout.
__global__ __launch_bounds__(512) void k_rowfin(const bf16* __restrict__ qrw,
                                                const bf16* __restrict__ krw,
                                                const float* __restrict__ x,
                                                const bf16* __restrict__ aggH,
                                                const float* __restrict__ lH,
                                                const bf16* __restrict__ wvb,
                                                const float* __restrict__ bv,
                                                const float* __restrict__ gamma,
                                                float* __restrict__ out){
    __shared__ __align__(16) bf16 Pl[16384];
    __shared__ __align__(16) bf16 AggL[16384];
    __shared__ float lsum[128];
    __shared__ float linv[128];
    int t = threadIdx.x;
    int wv = t >> 6, l = t & 63, lr = l & 15, lg = l >> 4;
    int h = blockIdx.x, b = blockIdx.y;
    f32x4 zero = {0.f,0.f,0.f,0.f};
    const size_t prow = (size_t)(b*NH + h)*NW;    // position base of row h
    // ---- p1: QK^T -> Pl (swizzled) ----
    bf16x8 af = *(const bf16x8*)(qrw + (prow + wv*16 + lr)*NQK + lg*8);
    float sreg[4] = {0.f,0.f,0.f,0.f};
    for (int nj=0; nj<8; nj++){
        bf16x8 bfr = *(const bf16x8*)(krw + (prow + nj*16 + lr)*NQK + lg*8);
        f32x4 e = __builtin_amdgcn_mfma_f32_16x16x32_bf16(af, bfr, zero, 0,0,0);
        #pragma unroll
        for (int r=0;r<4;r++){
            int i = wv*16 + lg*4 + r;
            int j = nj*16 + lr;
            float pv = __expf(e[r]);
            Pl[swz(i, j)] = f2b(pv);
            sreg[r] += pv;
        }
    }
    // prefetch aggH half0 (coalesced 16B/lane)
    uint4 ag[4];
    #pragma unroll
    for (int it=0;it<4;it++){
        int fl = it*512 + t, i = fl >> 4, seg = fl & 15;
        ag[it] = *(const uint4*)(aggH + (prow + i)*NC + seg*8);
    }
    // prefetch x rows half0 (aggW A-frags)
    float4 xf[8];
    {
        const float* xrow = x + ((size_t)(b*NC + wv*16 + lr))*NHW + h*NW;
        #pragma unroll
        for (int kb=0;kb<4;kb++){
            xf[2*kb]   = *(const float4*)(xrow + kb*32 + lg*8);
            xf[2*kb+1] = *(const float4*)(xrow + kb*32 + lg*8 + 4);
        }
    }
    #pragma unroll
    for (int m=1;m<16;m<<=1)
        #pragma unroll
        for (int r=0;r<4;r++) sreg[r] += __shfl_xor(sreg[r], m);
    if (lr == 0){
        #pragma unroll
        for (int r=0;r<4;r++) lsum[wv*16 + lg*4 + r] = sreg[r];
    }
    __syncthreads();                 // Pl, lsum visible
    if (t < 128) linv[t] = 1.f/(lH[((size_t)(b*NH + h))*NW + t] + lsum[t]);
    // stage aggH half0 into AggL (swizzled)
    #pragma unroll
    for (int it=0;it<4;it++){
        int fl = it*512 + t, i = fl >> 4, seg = fl & 15;
        *(uint4*)&AggL[i*128 + ((seg*8) ^ ((i&7)<<3))] = ag[it];
    }
    __syncthreads();                 // AggL + linv visible
    f32x4 Facc[8][2] = {};
    for (int half=0; half<2; half++){
        // pack this half's x frags
        bf16x8 xa[4];
        #pragma unroll
        for (int kb=0;kb<4;kb++){
            float4 u0 = xf[2*kb], u1 = xf[2*kb+1];
            union { bf16x8 v; bf16 hh[8]; } u;
            u.hh[0]=f2b(u0.x); u.hh[1]=f2b(u0.y); u.hh[2]=f2b(u0.z); u.hh[3]=f2b(u0.w);
            u.hh[4]=f2b(u1.x); u.hh[5]=f2b(u1.y); u.hh[6]=f2b(u1.z); u.hh[7]=f2b(u1.w);
            xa[kb] = u.v;
        }
        // prefetch aggH half1 during half0 compute
        if (half == 0){
            #pragma unroll
            for (int it=0;it<4;it++){
                int fl = it*512 + t, i = fl >> 4, seg = fl & 15;
                ag[it] = *(const uint4*)(aggH + (prow + i)*NC + 128 + seg*8);
            }
        }
        // aggW + combine + normalize (LDS RMW)
        for (int nj=0;nj<8;nj++){
            f32x4 acc = zero;
            #pragma unroll
            for (int kb=0;kb<4;kb++){
                bf16x8 pb = *(const bf16x8*)&Pl[swz(nj*16 + lr, kb*32 + lg*8)];
                acc = __builtin_amdgcn_mfma_f32_16x16x32_bf16(xa[kb], pb, acc, 0,0,0);
            }
            int i = nj*16 + lr, c4 = wv*16 + lg*4;
            float li = linv[i];
            bf16* ap = &AggL[i*128 + (c4 ^ ((i&7)<<3))];
            union { ushort4 u; bf16 hh[4]; } old, nu;
            old.u = *(const ushort4*)ap;
            #pragma unroll
            for (int r=0;r<4;r++) nu.hh[r] = f2b((b2f(old.hh[r]) + acc[r]) * li);
            *(ushort4*)ap = nu.u;
        }
        __syncthreads();             // RMW done before Wv reads
        // prefetch x rows half1 (hidden under Wv GEMM)
        if (half == 0){
            const float* xrow1 = x + ((size_t)(b*NC + 128 + wv*16 + lr))*NHW + h*NW;
            #pragma unroll
            for (int kb=0;kb<4;kb++){
                xf[2*kb]   = *(const float4*)(xrow1 + kb*32 + lg*8);
                xf[2*kb+1] = *(const float4*)(xrow1 + kb*32 + lg*8 + 4);
            }
        }
        // partial Wv GEMM over this half (K=128)
        for (int kb2=0; kb2<4; kb2++){
            bf16x8 bw[2];
            #pragma unroll
            for (int nt=0;nt<2;nt++)
                bw[nt] = *(const bf16x8*)(wvb + (size_t)(wv*32 + nt*16 + lr)*NC + half*128 + kb2*32 + lg*8);
            #pragma unroll
            for (int pt=0;pt<8;pt++){
                bf16x8 aa = *(const bf16x8*)&AggL[swz(pt*16 + lr, kb2*32 + lg*8)];
                Facc[pt][0] = __builtin_amdgcn_mfma_f32_16x16x32_bf16(aa, bw[0], Facc[pt][0], 0,0,0);
                Facc[pt][1] = __builtin_amdgcn_mfma_f32_16x16x32_bf16(aa, bw[1], Facc[pt][1], 0,0,0);
            }
        }
        if (half == 0){
            __syncthreads();         // Wv reads done before restage
            #pragma unroll
            for (int it=0;it<4;it++){
                int fl = it*512 + t, i = fl >> 4, seg = fl & 15;
                *(uint4*)&AggL[i*128 + ((seg*8) ^ ((i&7)<<3))] = ag[it];
            }
            __syncthreads();
        }
    }
    // epilogue: out = g*(Facc+bv) + x, float4 along p (full 64B lines)
    float g = gamma[0];
    #pragma unroll
    for (int nt=0;nt<2;nt++){
        int co = wv*32 + nt*16 + lr;
        float bvv = bv[co];
        const float* xr   = x   + ((size_t)(b*NC + co))*NHW + h*NW;
        float*       orow = out + ((size_t)(b*NC + co))*NHW + h*NW;
        #pragma unroll
        for (int pt=0;pt<8;pt++){
            int p4 = pt*16 + lg*4;
            float4 xv = *(const float4*)(xr + p4);
            float4 ov;
            ov.x = g*(Facc[pt][nt][0] + bvv) + xv.x;
            ov.y = g*(Facc[pt][nt][1] + bvv) + xv.y;
            ov.z = g*(Facc[pt][nt][2] + bvv) + xv.z;
            ov.w = g*(Facc[pt][nt][3] + bvv) + xv.w;
            *(float4*)(orow + p4) = ov;
        }
    }
}

extern "C" void kernel_launch(void* const* d_in, const int* in_sizes, int n_in,
                              void* d_out, int out_size, void* d_ws, size_t ws_size,
                              hipStream_t stream){
    (void)in_sizes; (void)n_in; (void)out_size; (void)ws_size;
    const float* x     = (const float*)d_in[0];
    const float* Wq    = (const float*)d_in[1];
    const float* bq    = (const float*)d_in[2];
    const float* Wk    = (const float*)d_in[3];
    const float* bk    = (const float*)d_in[4];
    const float* Wv    = (const float*)d_in[5];
    const float* bv    = (const float*)d_in[6];
    const float* gamma = (const float*)d_in[7];
    float* out = (float*)d_out;
    char* ws = (char*)d_ws;

    bf16*  qrw  = (bf16*) (ws + 0);          //  8,388,608  [b][p][32]
    bf16*  krw  = (bf16*) (ws + 8388608);    //  8,388,608  [b][p][32]
    bf16*  xcm  = (bf16*) (ws + 16777216);   // 67,108,864  [b][c][w][h]
    float* lH   = (float*)(ws + 83886080);   //    524,288  [b][i][w]
    bf16*  wvb  = (bf16*) (ws + 84410368);   //    131,072  [co][c]
    bf16*  wqkb = (bf16*) (ws + 84541440);   //     32,768  [64][256]
    bf16*  aggH = (bf16*) (ws + 84574208);   // 67,108,864  [b][p][c] unnormalized column agg
    // total ws: 151,683,072 bytes

    k_prep  <<<dim3(320),      dim3(256),   0, stream>>>(Wq, Wk, Wv, wvb, wqkb);
    k_qk    <<<dim3(64, 8),    dim3(512),   0, stream>>>(x, wqkb, bq, bk, qrw, krw);
    k_tr    <<<dim3(16, 2048), dim3(32, 8), 0, stream>>>(x, xcm);
    k_colagg<<<dim3(128, 8),   dim3(512),   0, stream>>>(qrw, krw, xcm, aggH, lH);
    k_rowfin<<<dim3(128, 8),   dim3(512),   0, stream>>>(qrw, krw, x, aggH, lH, wvb, bv, gamma, out);
}